// Round 1
// 272.880 us; speedup vs baseline: 1.0281x; 1.0281x over previous
//
#include <hip/hip_runtime.h>

// GaborLayer: out[p][o] = sin(x[p]·W[o] + b[o]) * exp(-0.5*gamma[o]*||x[p]-mu[o]||^2)
// P = 262144 points, OUT = 256, IN = 3. Output = 256 MiB fp32 -> write-BW bound.
//
// R2 design changes vs R1 (282 us):
//  - PLAIN stores, not nontemporal. The harness's fillBuffer kernels prove plain
//    stores sustain 6.3 TB/s pure-write; NT stores ack from HBM depth, so the
//    compiler's vmcnt wait before reusing store-data regs serialized each wave
//    against HBM latency (effective ~2.4 TB/s at 4 waves/SIMD).
//  - Constants pre-folded into hardware-transcendental domain:
//      * W,b scaled by 1/2pi -> raw v_sin_f32 (sin(2pi*x) semantics per ISA).
//      * -0.5*gamma*log2(e) folded into Gaussian coeffs -> raw v_exp_f32 (exp2),
//        mu also pre-multiplied so exp-arg = 4 FMAs total.
//    9 VALU ops/output instead of ~12.
//  - Scalar x loads software-pipelined one iteration ahead (s_load latency
//    hidden under compute, lgkmcnt off the critical path).

#define OUT_F 256

typedef float v4f __attribute__((ext_vector_type(4)));

__global__ __launch_bounds__(256, 4) void gabor_kernel(
    const float* __restrict__ x,      // (P, 3)
    const float* __restrict__ W,      // (256, 3)
    const float* __restrict__ b,      // (256,)
    const float* __restrict__ mu,     // (256, 3)
    const float* __restrict__ gamma,  // (256,)
    float* __restrict__ out,          // (P, 256)
    int P)
{
    const int lane        = threadIdx.x & 63;
    const int waveInBlock = threadIdx.x >> 6;
    const int wavesPerBlk = blockDim.x >> 6;
    const int wavesTotal  = gridDim.x * wavesPerBlk;
    // Force wave-uniformity so x addressing is scalar (s_load, lgkmcnt).
    const int waveId = __builtin_amdgcn_readfirstlane(blockIdx.x * wavesPerBlk + waveInBlock);

    const int o = lane << 2;  // 4 consecutive out-features per lane

    constexpr float INV_2PI = 0.15915493667125702f;  // 1/(2*pi)
    constexpr float LOG2E   = 1.4426950408889634f;   // log2(e)

    // Per-feature constants, pre-folded (~36 VGPRs, live whole kernel):
    //   lin_rev = wr·x + brv            (revolutions; feeds v_sin directly)
    //   ea      = aj*||x||^2 + n·x + dj (log2 units; feeds v_exp directly)
    float wr0[4], wr1[4], wr2[4], brv[4];
    float n0[4], n1[4], n2[4], dj[4], aj[4];
#pragma unroll
    for (int j = 0; j < 4; ++j) {
        const int oj = o + j;
        const float g2  = -0.5f * LOG2E * gamma[oj];   // log2-domain gaussian coeff
        const float m0v = mu[oj * 3 + 0];
        const float m1v = mu[oj * 3 + 1];
        const float m2v = mu[oj * 3 + 2];
        wr0[j] = W[oj * 3 + 0] * INV_2PI;
        wr1[j] = W[oj * 3 + 1] * INV_2PI;
        wr2[j] = W[oj * 3 + 2] * INV_2PI;
        brv[j] = b[oj] * INV_2PI;
        aj[j]  = g2;                                   // * ||x||^2
        n0[j]  = -2.0f * g2 * m0v;                     // * x0
        n1[j]  = -2.0f * g2 * m1v;                     // * x1
        n2[j]  = -2.0f * g2 * m2v;                     // * x2
        dj[j]  = g2 * (m0v * m0v + m1v * m1v + m2v * m2v);
    }

    // Contiguous chunk of points per wave (x reads walk forward -> s_load merge).
    const int ppw  = (P + wavesTotal - 1) / wavesTotal;
    const int p0   = waveId * ppw;
    const int pend = (p0 + ppw < P) ? (p0 + ppw) : P;

    int p = p0;
    if (p + 4 <= pend) {
        // Prologue: load first 4 points of x (12 wave-uniform scalar loads).
        float xv[12];
        {
            const float* xp = x + (size_t)p * 3;
#pragma unroll
            for (int i = 0; i < 12; ++i) xv[i] = xp[i];
        }

        while (p + 4 <= pend) {
            const int pn = p + 4;
            // Prefetch next iteration's x while this iteration computes.
            // Clamp so the prefetch never reads past the array (P >= 4 always).
            const int pf = (pn + 4 <= P) ? pn : (P - 4);
            float xn[12];
            {
                const float* xq = x + (size_t)pf * 3;
#pragma unroll
                for (int i = 0; i < 12; ++i) xn[i] = xq[i];
            }

            float* orow = out + (size_t)p * OUT_F + o;
#pragma unroll
            for (int q = 0; q < 4; ++q) {
                const float x0 = xv[q * 3 + 0];
                const float x1 = xv[q * 3 + 1];
                const float x2 = xv[q * 3 + 2];
                const float xs = x0 * x0 + x1 * x1 + x2 * x2;
                v4f r;
#pragma unroll
                for (int j = 0; j < 4; ++j) {
                    const float lin = fmaf(wr0[j], x0, fmaf(wr1[j], x1, fmaf(wr2[j], x2, brv[j])));
                    const float t   = fmaf(n0[j], x0, fmaf(n1[j], x1, fmaf(n2[j], x2, dj[j])));
                    const float ea  = fmaf(aj[j], xs, t);
                    r[j] = __builtin_amdgcn_sinf(lin) * __builtin_amdgcn_exp2f(ea);
                }
                // Plain coalesced store: 64 lanes x 16B = one contiguous 1 KiB row.
                *reinterpret_cast<v4f*>(orow + (size_t)q * OUT_F) = r;
            }

            p = pn;
#pragma unroll
            for (int i = 0; i < 12; ++i) xv[i] = xn[i];
        }
    }

    // Tail (P divides evenly in practice; kept for safety).
    for (; p < pend; ++p) {
        const float x0 = x[p * 3 + 0];
        const float x1 = x[p * 3 + 1];
        const float x2 = x[p * 3 + 2];
        const float xs = x0 * x0 + x1 * x1 + x2 * x2;
        v4f r;
#pragma unroll
        for (int j = 0; j < 4; ++j) {
            const float lin = fmaf(wr0[j], x0, fmaf(wr1[j], x1, fmaf(wr2[j], x2, brv[j])));
            const float t   = fmaf(n0[j], x0, fmaf(n1[j], x1, fmaf(n2[j], x2, dj[j])));
            const float ea  = fmaf(aj[j], xs, t);
            r[j] = __builtin_amdgcn_sinf(lin) * __builtin_amdgcn_exp2f(ea);
        }
        *reinterpret_cast<v4f*>(out + (size_t)p * OUT_F + o) = r;
    }
}

extern "C" void kernel_launch(void* const* d_in, const int* in_sizes, int n_in,
                              void* d_out, int out_size, void* d_ws, size_t ws_size,
                              hipStream_t stream) {
    const float* x     = (const float*)d_in[0];
    const float* W     = (const float*)d_in[1];
    const float* b     = (const float*)d_in[2];
    const float* mu    = (const float*)d_in[3];
    const float* gamma = (const float*)d_in[4];
    float* out = (float*)d_out;

    const int P = in_sizes[0] / 3;  // B*N points

    // 2048 blocks x 4 waves = 8192 waves -> 32 contiguous points per wave.
    gabor_kernel<<<2048, 256, 0, stream>>>(x, W, b, mu, gamma, out, P);
}

// Round 2
// 270.879 us; speedup vs baseline: 1.0357x; 1.0074x over previous
//
#include <hip/hip_runtime.h>

// GaborLayer: out[p][o] = sin(x[p]·W[o] + b[o]) * exp(-0.5*gamma[o]*||x[p]-mu[o]||^2)
// P = 262144 points, OUT = 256, IN = 3. Output = 256 MiB fp32 -> write-BW bound.
//
// R3: occupancy experiment. R2 showed the kernel (~106 us vs 43 us write roofline)
// is inelastic to instruction changes (NT vs plain stores, -25% VALU: only -7 us)
// -> latency/TLP-bound, not issue-bound. At __launch_bounds__(256,4) we had
// 4 waves/SIMD (4096 resident of 8192 launched, two generations). The harness's
// own fill kernel (8 VGPR, 8 waves/SIMD) sustains 6.4 TB/s pure-write.
//   - __launch_bounds__(256, 8): 8 waves/SIMD, all 8192 waves resident at once.
//   - Register diet to fit 64 VGPRs: 2-point unroll (was 4); pipelined x values
//     are wave-uniform s_load results living in SGPRs (free of VGPR budget).
//     Per-lane folded constants = 36 VGPRs + r(4) + addressing/temps ~ 50 total.
//   - Keep: plain dwordx4 stores (1 KiB/wave contiguous), constants pre-folded
//     into v_sin (revolutions) / v_exp (log2) domain, 1-iter-ahead x prefetch.

#define OUT_F 256

typedef float v4f __attribute__((ext_vector_type(4)));

__global__ __launch_bounds__(256, 8) void gabor_kernel(
    const float* __restrict__ x,      // (P, 3)
    const float* __restrict__ W,      // (256, 3)
    const float* __restrict__ b,      // (256,)
    const float* __restrict__ mu,     // (256, 3)
    const float* __restrict__ gamma,  // (256,)
    float* __restrict__ out,          // (P, 256)
    int P)
{
    const int lane        = threadIdx.x & 63;
    const int waveInBlock = threadIdx.x >> 6;
    const int wavesPerBlk = blockDim.x >> 6;
    const int wavesTotal  = gridDim.x * wavesPerBlk;
    // Force wave-uniformity so x addressing is scalar (s_load, lgkmcnt).
    const int waveId = __builtin_amdgcn_readfirstlane(blockIdx.x * wavesPerBlk + waveInBlock);

    const int o = lane << 2;  // 4 consecutive out-features per lane

    constexpr float INV_2PI = 0.15915493667125702f;  // 1/(2*pi)
    constexpr float LOG2E   = 1.4426950408889634f;   // log2(e)

    // Per-feature constants, pre-folded (36 VGPRs, live whole kernel):
    //   lin_rev = wr·x + brv            (revolutions; feeds v_sin directly)
    //   ea      = aj*||x||^2 + n·x + dj (log2 units; feeds v_exp directly)
    float wr0[4], wr1[4], wr2[4], brv[4];
    float n0[4], n1[4], n2[4], dj[4], aj[4];
#pragma unroll
    for (int j = 0; j < 4; ++j) {
        const int oj = o + j;
        const float g2  = -0.5f * LOG2E * gamma[oj];
        const float m0v = mu[oj * 3 + 0];
        const float m1v = mu[oj * 3 + 1];
        const float m2v = mu[oj * 3 + 2];
        wr0[j] = W[oj * 3 + 0] * INV_2PI;
        wr1[j] = W[oj * 3 + 1] * INV_2PI;
        wr2[j] = W[oj * 3 + 2] * INV_2PI;
        brv[j] = b[oj] * INV_2PI;
        aj[j]  = g2;
        n0[j]  = -2.0f * g2 * m0v;
        n1[j]  = -2.0f * g2 * m1v;
        n2[j]  = -2.0f * g2 * m2v;
        dj[j]  = g2 * (m0v * m0v + m1v * m1v + m2v * m2v);
    }

    // Contiguous chunk of points per wave (x reads walk forward -> s_load merge).
    const int ppw  = (P + wavesTotal - 1) / wavesTotal;
    const int p0   = waveId * ppw;
    const int pend = (p0 + ppw < P) ? (p0 + ppw) : P;

    int p = p0;
    if (p + 2 <= pend) {
        // Prologue: 6 wave-uniform scalar loads (2 points of x) -> SGPRs.
        float xv[6];
        {
            const float* xp = x + (size_t)p * 3;
#pragma unroll
            for (int i = 0; i < 6; ++i) xv[i] = xp[i];
        }

        while (p + 2 <= pend) {
            const int pn = p + 2;
            // Prefetch next iteration's x while this one computes (clamped).
            const int pf = (pn + 2 <= P) ? pn : (P - 2);
            float xn[6];
            {
                const float* xq = x + (size_t)pf * 3;
#pragma unroll
                for (int i = 0; i < 6; ++i) xn[i] = xq[i];
            }

            float* orow = out + (size_t)p * OUT_F + o;
#pragma unroll
            for (int q = 0; q < 2; ++q) {
                const float x0 = xv[q * 3 + 0];
                const float x1 = xv[q * 3 + 1];
                const float x2 = xv[q * 3 + 2];
                const float xs = x0 * x0 + x1 * x1 + x2 * x2;
                v4f r;
#pragma unroll
                for (int j = 0; j < 4; ++j) {
                    const float lin = fmaf(wr0[j], x0, fmaf(wr1[j], x1, fmaf(wr2[j], x2, brv[j])));
                    const float t   = fmaf(n0[j], x0, fmaf(n1[j], x1, fmaf(n2[j], x2, dj[j])));
                    const float ea  = fmaf(aj[j], xs, t);
                    r[j] = __builtin_amdgcn_sinf(lin) * __builtin_amdgcn_exp2f(ea);
                }
                // Plain coalesced store: 64 lanes x 16B = one contiguous 1 KiB row.
                *reinterpret_cast<v4f*>(orow + (size_t)q * OUT_F) = r;
            }

            p = pn;
#pragma unroll
            for (int i = 0; i < 6; ++i) xv[i] = xn[i];
        }
    }

    // Tail (P divides evenly in practice; kept for safety).
    for (; p < pend; ++p) {
        const float x0 = x[p * 3 + 0];
        const float x1 = x[p * 3 + 1];
        const float x2 = x[p * 3 + 2];
        const float xs = x0 * x0 + x1 * x1 + x2 * x2;
        v4f r;
#pragma unroll
        for (int j = 0; j < 4; ++j) {
            const float lin = fmaf(wr0[j], x0, fmaf(wr1[j], x1, fmaf(wr2[j], x2, brv[j])));
            const float t   = fmaf(n0[j], x0, fmaf(n1[j], x1, fmaf(n2[j], x2, dj[j])));
            const float ea  = fmaf(aj[j], xs, t);
            r[j] = __builtin_amdgcn_sinf(lin) * __builtin_amdgcn_exp2f(ea);
        }
        *reinterpret_cast<v4f*>(out + (size_t)p * OUT_F + o) = r;
    }
}

extern "C" void kernel_launch(void* const* d_in, const int* in_sizes, int n_in,
                              void* d_out, int out_size, void* d_ws, size_t ws_size,
                              hipStream_t stream) {
    const float* x     = (const float*)d_in[0];
    const float* W     = (const float*)d_in[1];
    const float* b     = (const float*)d_in[2];
    const float* mu    = (const float*)d_in[3];
    const float* gamma = (const float*)d_in[4];
    float* out = (float*)d_out;

    const int P = in_sizes[0] / 3;  // B*N points

    // 2048 blocks x 4 waves = 8192 waves; at 8 waves/SIMD all are resident
    // simultaneously (256 CU x 4 SIMD x 8 = 8192). 32 contiguous points/wave.
    gabor_kernel<<<2048, 256, 0, stream>>>(x, W, b, mu, gamma, out, P);
}